// Round 2
// baseline (1973.574 us; speedup 1.0000x reference)
//
#include <hip/hip_runtime.h>
#include <hip/hip_bf16.h>

// Dtype theory (round 2): reference is jnp.float32 everywhere -> harness passes
// fp32 inputs and expects fp32 output. Round-1 NaN is exactly what fp32-read-
// as-bf16 produces (low-half words with exp=0xFF). Compute stays bf16 MFMA,
// weights pre-converted once to a bf16 arena in d_ws.

typedef __hip_bfloat16 bf16;
typedef __attribute__((ext_vector_type(8))) short short8;
typedef __attribute__((ext_vector_type(4))) float f32x4;

__device__ __forceinline__ float bf2f(bf16 x){ return __bfloat162float(x); }
__device__ __forceinline__ bf16  f2bf(float x){ return __float2bfloat16(x); }

__device__ __forceinline__ void gld16(const bf16* g, bf16* l){
  __builtin_amdgcn_global_load_lds(
      (const __attribute__((address_space(1))) void*)g,
      (__attribute__((address_space(3))) void*)l, 16, 0, 0);
}

__device__ __forceinline__ float sigm(float x){ return 1.0f/(1.0f + __expf(-x)); }
__device__ __forceinline__ float tanhfast(float x){
  x = fminf(fmaxf(x, -15.f), 15.f);
  float e = __expf(2.f*x);
  return (e-1.f)/(e+1.f);
}

// ---------------------------------------------------------------------------
// Batched fp32 -> bf16 weight conversion into arena (element counts static).
// Tensor order = d_in[6..30]; arena offset of tensor i = CVT_CUM[i]*4 elems.
// ---------------------------------------------------------------------------
struct CvtPtrs { const float* p[25]; };
__constant__ long CVT_CUM[26] = {0, 98304, 98432, 360576, 360704, 426240,
  426368, 1450368, 1452368, 2476368, 2478368, 3502368, 3504368, 3760368,
  3760496, 4784496, 4786496, 5786496, 5786996, 6042996, 6043124, 7067124,
  7069124, 8069124, 8069624, 8070624};

__global__ __launch_bounds__(256) void cvt_all(CvtPtrs P, bf16* __restrict__ arena)
{
  long g = (long)blockIdx.x * 256 + threadIdx.x;
  if (g >= 8070624l) return;
  int lo = 0, hi = 24;
  while (lo < hi) { int mid = (lo + hi + 1) >> 1; if (g >= CVT_CUM[mid]) lo = mid; else hi = mid - 1; }
  long rel = (g - CVT_CUM[lo]) * 4;
  float4 v = *(const float4*)(P.p[lo] + rel);
  union { bf16 h[4]; uint2 u; } t;
  t.h[0]=f2bf(v.x); t.h[1]=f2bf(v.y); t.h[2]=f2bf(v.z); t.h[3]=f2bf(v.w);
  *(uint2*)(arena + CVT_CUM[lo]*4 + rel) = t.u;
}

// ---------------------------------------------------------------------------
// bt-GEMM, fp32 A / bf16 B(arena): C[M,N] = A @ Bt^T + bias (bf16 out).
// 128x128 tile, BK=32. A staged via float4 loads + cvt + ds_write_b128.
// Requires K%32==0, M%128==0 here (call sites satisfy).
// ---------------------------------------------------------------------------
__global__ __launch_bounds__(256) void gemm_linA32(
    const float* __restrict__ A, const bf16* __restrict__ Bt,
    const bf16* __restrict__ bias, bf16* __restrict__ C,
    int M, int N, int K, int lda, int ldb, int ldc)
{
  __shared__ bf16 sm[(128+128)*32];
  bf16* As = sm; bf16* Bs = sm + 128*32;
  const int tid  = threadIdx.x;
  const int wave = tid >> 6, lane = tid & 63;
  const int wr = (wave >> 1) * 64, wc = (wave & 1) * 64;
  const int ln = lane & 15, lq = lane >> 4;
  const long m0 = (long)blockIdx.x * 128;
  const int  n0 = blockIdx.y * 128;
  const int arow = tid >> 1, ahalf = (tid & 1) * 16;
  f32x4 acc[4][4] = {};
  for (int ks = 0; ks < (K >> 5); ++ks) {
    const int k0 = ks * 32;
    __syncthreads();
    {  // A: 128 rows x 32 fp32 -> bf16
      const float* s = A + (m0 + arow) * (long)lda + k0 + ahalf;
      float4 v0 = *(const float4*)(s);
      float4 v1 = *(const float4*)(s + 4);
      float4 v2 = *(const float4*)(s + 8);
      float4 v3 = *(const float4*)(s + 12);
      union { bf16 h[16]; short8 q[2]; } u;
      u.h[0]=f2bf(v0.x); u.h[1]=f2bf(v0.y); u.h[2]=f2bf(v0.z); u.h[3]=f2bf(v0.w);
      u.h[4]=f2bf(v1.x); u.h[5]=f2bf(v1.y); u.h[6]=f2bf(v1.z); u.h[7]=f2bf(v1.w);
      u.h[8]=f2bf(v2.x); u.h[9]=f2bf(v2.y); u.h[10]=f2bf(v2.z); u.h[11]=f2bf(v2.w);
      u.h[12]=f2bf(v3.x); u.h[13]=f2bf(v3.y); u.h[14]=f2bf(v3.z); u.h[15]=f2bf(v3.w);
      *(short8*)(As + arow*32 + ahalf)     = u.q[0];
      *(short8*)(As + arow*32 + ahalf + 8) = u.q[1];
    }
#pragma unroll
    for (int p = 0; p < 2; ++p) {            // B: 128 rows x 4 chunks
      int t = p * 256 + tid;
      int row = t >> 2, ch = (t & 3) * 8;
      int col = n0 + row; col = (col < N) ? col : (N - 1);
      gld16(Bt + (long)col * ldb + k0 + ch, Bs + t * 8);
    }
    __syncthreads();
    short8 af[4], bv[4];
#pragma unroll
    for (int i = 0; i < 4; ++i)
      af[i] = *(const short8*)(As + (wr + i*16 + ln) * 32 + lq * 8);
#pragma unroll
    for (int j = 0; j < 4; ++j)
      bv[j] = *(const short8*)(Bs + (wc + j*16 + ln) * 32 + lq * 8);
#pragma unroll
    for (int i = 0; i < 4; ++i)
#pragma unroll
      for (int j = 0; j < 4; ++j)
        acc[i][j] = __builtin_amdgcn_mfma_f32_16x16x32_bf16(af[i], bv[j], acc[i][j], 0, 0, 0);
  }
#pragma unroll
  for (int j = 0; j < 4; ++j) {
    int n = n0 + wc + j * 16 + ln;
    if (n < N) {
      float bvv = bf2f(bias[n]);
#pragma unroll
      for (int i = 0; i < 4; ++i)
#pragma unroll
        for (int r = 0; r < 4; ++r) {
          long m = m0 + wr + i * 16 + lq * 4 + r;
          C[m * ldc + n] = f2bf(acc[i][j][r] + bvv);
        }
    } else if (n < ldc) {
#pragma unroll
      for (int i = 0; i < 4; ++i)
#pragma unroll
        for (int r = 0; r < 4; ++r) {
          long m = m0 + wr + i * 16 + lq * 4 + r;
          C[m * ldc + n] = f2bf(0.f);
        }
    }
  }
}

// ---------------------------------------------------------------------------
// bt-GEMM, bf16 A / bf16 B: same tile; A rows must be zero-padded over
// [K, 32*ceil(K/32)) (our ld-2016 buffers guarantee this for K=2000).
// ---------------------------------------------------------------------------
__global__ __launch_bounds__(256) void gemm_lin(
    const bf16* __restrict__ A, const bf16* __restrict__ Bt,
    const bf16* __restrict__ bias, bf16* __restrict__ C,
    int M, int N, int K, int lda, int ldb, int ldc)
{
  __shared__ bf16 sm[(128+128)*32];
  bf16* As = sm; bf16* Bs = sm + 128*32;
  const int tid  = threadIdx.x;
  const int wave = tid >> 6, lane = tid & 63;
  const int wr = (wave >> 1) * 64, wc = (wave & 1) * 64;
  const int ln = lane & 15, lq = lane >> 4;
  const long m0 = (long)blockIdx.x * 128;
  const int  n0 = blockIdx.y * 128;
  f32x4 acc[4][4] = {};
  const int ksteps = (K + 31) >> 5;
  for (int ks = 0; ks < ksteps; ++ks) {
    const int k0 = ks * 32;
    __syncthreads();
#pragma unroll
    for (int p = 0; p < 2; ++p) {            // A tile
      int t = p * 256 + tid;
      gld16(A + (m0 + (t >> 2)) * (long)lda + k0 + (t & 3) * 8, As + t * 8);
    }
#pragma unroll
    for (int p = 0; p < 2; ++p) {            // B tile
      int t = p * 256 + tid;
      int row = t >> 2, ch = (t & 3) * 8;
      int col = n0 + row; col = (col < N) ? col : (N - 1);
      int kk = k0 + ch; kk = (kk + 8 <= K) ? kk : 0;   // A is zero there
      gld16(Bt + (long)col * ldb + kk, Bs + t * 8);
    }
    __syncthreads();
    short8 af[4], bv[4];
#pragma unroll
    for (int i = 0; i < 4; ++i)
      af[i] = *(const short8*)(As + (wr + i*16 + ln) * 32 + lq * 8);
#pragma unroll
    for (int j = 0; j < 4; ++j)
      bv[j] = *(const short8*)(Bs + (wc + j*16 + ln) * 32 + lq * 8);
#pragma unroll
    for (int i = 0; i < 4; ++i)
#pragma unroll
      for (int j = 0; j < 4; ++j)
        acc[i][j] = __builtin_amdgcn_mfma_f32_16x16x32_bf16(af[i], bv[j], acc[i][j], 0, 0, 0);
  }
#pragma unroll
  for (int j = 0; j < 4; ++j) {
    int n = n0 + wc + j * 16 + ln;
    if (n < N) {
      float bvv = bf2f(bias[n]);
#pragma unroll
      for (int i = 0; i < 4; ++i)
#pragma unroll
        for (int r = 0; r < 4; ++r) {
          long m = m0 + wr + i * 16 + lq * 4 + r;
          C[m * ldc + n] = f2bf(acc[i][j][r] + bvv);
        }
    } else if (n < ldc) {
#pragma unroll
      for (int i = 0; i < 4; ++i)
#pragma unroll
        for (int r = 0; r < 4; ++r) {
          long m = m0 + wr + i * 16 + lq * 4 + r;
          C[m * ldc + n] = f2bf(0.f);
        }
    }
  }
}

// ---------------------------------------------------------------------------
// Fused single-step BiLSTM gate GEMM + activation (f-gate dead since h0=c0=0).
// A:[M,512] bf16. W:[8000,512] arena bf16. Tile 128 rows x 32 h-cols (96 gate
// cols, per wave 64x48 = 4x3 frags). grid.y = dir*32 + jb.
// ---------------------------------------------------------------------------
__global__ __launch_bounds__(256) void gemm_lstm(
    const bf16* __restrict__ A, const bf16* __restrict__ W,
    const bf16* __restrict__ bvec, const bf16* __restrict__ other,
    bf16* __restrict__ Hout, int ldo, int ldc, int combine)
{
  __shared__ bf16 sm[(128+96)*32];
  bf16* As = sm; bf16* Bs = sm + 128*32;
  const int tid  = threadIdx.x;
  const int wave = tid >> 6, lane = tid & 63;
  const int wr = (wave >> 1) * 64, wc = (wave & 1) * 48;
  const int ln = lane & 15, lq = lane >> 4;
  const long m0 = (long)blockIdx.x * 128;
  const int dir = blockIdx.y >> 5, jb = blockIdx.y & 31;
  f32x4 acc[4][3] = {};
  for (int ks = 0; ks < 16; ++ks) {          // K = 512
    const int k0 = ks * 32;
    __syncthreads();
#pragma unroll
    for (int p = 0; p < 2; ++p) {
      int t = p * 256 + tid;
      gld16(A + (m0 + (t >> 2)) * 512 + k0 + (t & 3) * 8, As + t * 8);
    }
    for (int t = tid; t < 384; t += 256) {   // 96 gate rows x 4 chunks
      int tc = t >> 2;
      int grp = tc / 48, wi = tc % 48, cf = wi >> 4;
      int jj = jb * 32 + grp * 16 + (wi & 15);
      jj = (jj < 1000) ? jj : 999;
      int row = dir * 4000 + cf * 1000 + (cf ? 1000 : 0) + jj;  // i,g,o = 0,2000,3000
      gld16(W + (long)row * 512 + k0 + (t & 3) * 8, Bs + t * 8);
    }
    __syncthreads();
    short8 af[4], bv[3];
#pragma unroll
    for (int i = 0; i < 4; ++i)
      af[i] = *(const short8*)(As + (wr + i*16 + ln) * 32 + lq * 8);
#pragma unroll
    for (int j = 0; j < 3; ++j)
      bv[j] = *(const short8*)(Bs + (wc + j*16 + ln) * 32 + lq * 8);
#pragma unroll
    for (int i = 0; i < 4; ++i)
#pragma unroll
      for (int j = 0; j < 3; ++j)
        acc[i][j] = __builtin_amdgcn_mfma_f32_16x16x32_bf16(af[i], bv[j], acc[i][j], 0, 0, 0);
  }
  const int jj  = jb * 32 + (wave & 1) * 16 + ln;
  const int jc  = (jj < 1000) ? jj : 999;
  const float bI = bf2f(bvec[dir * 4000 + jc]);
  const float bG = bf2f(bvec[dir * 4000 + 2000 + jc]);
  const float bO = bf2f(bvec[dir * 4000 + 3000 + jc]);
  const int col = dir * 1000 + jj;
  const bool sv = (jj < 1000);
  const bool sz = (!sv) && (dir == 1) && (col < ldc);
  if (!sv && !sz) return;
#pragma unroll
  for (int i = 0; i < 4; ++i)
#pragma unroll
    for (int r = 0; r < 4; ++r) {
      long m = m0 + wr + i * 16 + lq * 4 + r;
      float h = 0.f;
      if (sv) {
        float gi = acc[i][0][r] + bI;
        float gg = acc[i][1][r] + bG;
        float go = acc[i][2][r] + bO;
        float cc = sigm(gi) * tanhfast(gg);
        h = sigm(go) * tanhfast(cc);
        if (combine) h = 0.5f * (h + bf2f(other[m * ldo + col]));
      }
      Hout[m * ldc + col] = f2bf(h);
    }
}

// mean over 24 neighbors: X [512*24, 2000] bf16 -> Y [512,2000] fp32
__global__ __launch_bounds__(256) void mean24(const bf16* __restrict__ X, float* __restrict__ Y)
{
  long idx = (long)blockIdx.x * 256 + threadIdx.x;
  if (idx >= 512l * 2000) return;
  long b = idx / 2000, e = idx % 2000;
  const bf16* p = X + b * 24 * 2000 + e;
  float s = 0.f;
#pragma unroll
  for (int n = 0; n < 24; ++n) s += bf2f(p[(long)n * 2000]);
  Y[idx] = s * (1.f / 24.f);
}

// attention over {c, u_agg, p_agg} + weighted mix -> out [512,2000] fp32
__global__ __launch_bounds__(256) void attn_mix(
    const bf16* __restrict__ Cm, const float* __restrict__ U,
    const float* __restrict__ P, const float* __restrict__ att,
    float* __restrict__ out)
{
  const int b = blockIdx.x, tid = threadIdx.x;
  __shared__ float red[4][4];
  __shared__ float wsh[3];
  float s0 = 0, s1 = 0, s2 = 0, s3 = 0;
  const long base = (long)b * 2000;
  for (int e = tid; e < 2000; e += 256) {
    float cv = bf2f(Cm[base + e]);
    float al = att[e];
    float ah = att[2000 + e];
    s0 += cv * al; s1 += cv * ah;
    s2 += U[base + e] * ah; s3 += P[base + e] * ah;
  }
#pragma unroll
  for (int o = 32; o; o >>= 1) {
    s0 += __shfl_down(s0, o); s1 += __shfl_down(s1, o);
    s2 += __shfl_down(s2, o); s3 += __shfl_down(s3, o);
  }
  if ((tid & 63) == 0) {
    int w = tid >> 6;
    red[w][0] = s0; red[w][1] = s1; red[w][2] = s2; red[w][3] = s3;
  }
  __syncthreads();
  if (tid == 0) {
    float a0 = 0, a1 = 0, a2 = 0, a3 = 0;
    for (int w = 0; w < 4; ++w) { a0 += red[w][0]; a1 += red[w][1]; a2 += red[w][2]; a3 += red[w][3]; }
    float t0 = a0 + a1, t1 = a0 + a2, t2 = a0 + a3;
    t0 = t0 > 0 ? t0 : 0.01f * t0;
    t1 = t1 > 0 ? t1 : 0.01f * t1;
    t2 = t2 > 0 ? t2 : 0.01f * t2;
    float mx = fmaxf(t0, fmaxf(t1, t2));
    float e0 = __expf(t0 - mx), e1 = __expf(t1 - mx), e2 = __expf(t2 - mx);
    float inv = 1.f / (e0 + e1 + e2);
    wsh[0] = e0 * inv; wsh[1] = e1 * inv; wsh[2] = e2 * inv;
  }
  __syncthreads();
  float w0 = wsh[0], w1 = wsh[1], w2 = wsh[2];
  for (int e = tid; e < 2000; e += 256)
    out[base + e] = w0 * bf2f(Cm[base + e]) + w1 * U[base + e] + w2 * P[base + e];
}

extern "C" void kernel_launch(void* const* d_in, const int* in_sizes, int n_in,
                              void* d_out, int out_size, void* d_ws, size_t ws_size,
                              hipStream_t stream)
{
  const float* c_text  = (const float*)d_in[0];
  const float* c_image = (const float*)d_in[1];
  const float* p_text  = (const float*)d_in[2];
  const float* p_image = (const float*)d_in[3];
  const float* u_text  = (const float*)d_in[4];
  const float* u_other = (const float*)d_in[5];
  const float* p_att   = (const float*)d_in[30];
  float* out = (float*)d_out;

  char* ws = (char*)d_ws;
  size_t off = 0;
  auto alloc = [&](size_t bytes) -> char* {
    char* p = ws + off; off += (bytes + 255) & ~(size_t)255; return p;
  };
  bf16* ARENA = (bf16*)alloc(32282496ull * 2);     // bf16 weights
  bf16* BIG1  = (bf16*)alloc(12288ull * 2016 * 2);
  bf16* BIG2  = (bf16*)alloc(12288ull * 2016 * 2);
  bf16* X1    = (bf16*)alloc(12288ull * 512 * 2);
  bf16* X2    = (bf16*)alloc(12288ull * 512 * 2);
  bf16* Cc    = (bf16*)alloc(512ull * 2000 * 2);
  float* UA   = (float*)alloc(512ull * 2000 * 4);
  float* PA   = (float*)alloc(512ull * 2000 * 4);
  (void)ws_size; (void)in_sizes; (void)n_in; (void)out_size;

  // arena element offsets (= CVT_CUM[i]*4)
  const bf16* aW_lt = ARENA + 0;        const bf16* ab_lt = ARENA + 393216;
  const bf16* aW_li = ARENA + 393728;   const bf16* ab_li = ARENA + 1442304;
  const bf16* aW_lo = ARENA + 1442816;  const bf16* ab_lo = ARENA + 1704960;
  const bf16* alt_W = ARENA + 1705472;  const bf16* alt_b = ARENA + 5801472;
  const bf16* ali_W = ARENA + 5809472;  const bf16* ali_b = ARENA + 9905472;
  const bf16* alo_W = ARENA + 9913472;  const bf16* alo_b = ARENA + 14009472;
  const bf16* aua_lin_W  = ARENA + 14017472; const bf16* aua_lin_b  = ARENA + 15041472;
  const bf16* aua_lstm_W = ARENA + 15041984; const bf16* aua_lstm_b = ARENA + 19137984;
  const bf16* aua_out_W  = ARENA + 19145984; const bf16* aua_out_b  = ARENA + 23145984;
  const bf16* apa_lin_W  = ARENA + 23147984; const bf16* apa_lin_b  = ARENA + 24171984;
  const bf16* apa_lstm_W = ARENA + 24172496; const bf16* apa_lstm_b = ARENA + 28268496;
  const bf16* apa_out_W  = ARENA + 28276496; const bf16* apa_out_b  = ARENA + 32276496;

  CvtPtrs cp;
  for (int i = 0; i < 25; ++i) cp.p[i] = (const float*)d_in[6 + i];
  cvt_all<<<dim3(31527), dim3(256), 0, stream>>>(cp, ARENA);

  dim3 blk(256);
  // ---- center (post) path, M=512
  gemm_linA32<<<dim3(4,4),  blk, 0, stream>>>(c_text,  aW_lt, ab_lt, X1, 512, 512, 768,  768,  768,  512);
  gemm_linA32<<<dim3(4,4),  blk, 0, stream>>>(c_image, aW_li, ab_li, X2, 512, 512, 2048, 2048, 2048, 512);
  gemm_lstm<<<dim3(4,64), blk, 0, stream>>>(X1, alt_W, alt_b, nullptr, BIG1, 2016, 2016, 0);
  gemm_lstm<<<dim3(4,64), blk, 0, stream>>>(X2, ali_W, ali_b, BIG1,    Cc,   2016, 2000, 1);

  // ---- user path, M=12288
  gemm_linA32<<<dim3(96,4), blk, 0, stream>>>(u_text,  aW_lt, ab_lt, X1, 12288, 512, 768, 768, 768, 512);
  gemm_linA32<<<dim3(96,4), blk, 0, stream>>>(u_other, aW_lo, ab_lo, X2, 12288, 512, 512, 512, 512, 512);
  gemm_lstm<<<dim3(96,64), blk, 0, stream>>>(X1, alt_W, alt_b, nullptr, BIG1, 2016, 2016, 0);
  gemm_lstm<<<dim3(96,64), blk, 0, stream>>>(X2, alo_W, alo_b, BIG1,    BIG2, 2016, 2016, 1);
  gemm_lin<<<dim3(96,4), blk, 0, stream>>>(BIG2, aua_lin_W, aua_lin_b, X1, 12288, 512, 2000, 2016, 2000, 512);
  gemm_lstm<<<dim3(96,64), blk, 0, stream>>>(X1, aua_lstm_W, aua_lstm_b, nullptr, BIG1, 2016, 2016, 0);
  gemm_lin<<<dim3(96,16), blk, 0, stream>>>(BIG1, aua_out_W, aua_out_b, BIG2, 12288, 2000, 2000, 2016, 2000, 2000);
  mean24<<<dim3(4000), blk, 0, stream>>>(BIG2, UA);

  // ---- post-neighbor path, M=12288
  gemm_linA32<<<dim3(96,4), blk, 0, stream>>>(p_text,  aW_lt, ab_lt, X1, 12288, 512, 768,  768,  768,  512);
  gemm_linA32<<<dim3(96,4), blk, 0, stream>>>(p_image, aW_li, ab_li, X2, 12288, 512, 2048, 2048, 2048, 512);
  gemm_lstm<<<dim3(96,64), blk, 0, stream>>>(X1, alt_W, alt_b, nullptr, BIG1, 2016, 2016, 0);
  gemm_lstm<<<dim3(96,64), blk, 0, stream>>>(X2, ali_W, ali_b, BIG1,    BIG2, 2016, 2016, 1);
  gemm_lin<<<dim3(96,4), blk, 0, stream>>>(BIG2, apa_lin_W, apa_lin_b, X1, 12288, 512, 2000, 2016, 2000, 512);
  gemm_lstm<<<dim3(96,64), blk, 0, stream>>>(X1, apa_lstm_W, apa_lstm_b, nullptr, BIG1, 2016, 2016, 0);
  gemm_lin<<<dim3(96,16), blk, 0, stream>>>(BIG1, apa_out_W, apa_out_b, BIG2, 12288, 2000, 2000, 2016, 2000, 2000);
  mean24<<<dim3(4000), blk, 0, stream>>>(BIG2, PA);

  // ---- attention + mix (fp32 out)
  attn_mix<<<dim3(512), blk, 0, stream>>>(Cc, UA, PA, p_att, out);
}

// Round 3
// 1919.081 us; speedup vs baseline: 1.0284x; 1.0284x over previous
//
#include <hip/hip_runtime.h>
#include <hip/hip_bf16.h>

// Round 3: hoist all K-invariant staging addresses out of the GEMM K-loops
// (per-thread base pointers advanced by +32 elems/step). No numeric changes.

typedef __hip_bfloat16 bf16;
typedef __attribute__((ext_vector_type(8))) short short8;
typedef __attribute__((ext_vector_type(4))) float f32x4;

__device__ __forceinline__ float bf2f(bf16 x){ return __bfloat162float(x); }
__device__ __forceinline__ bf16  f2bf(float x){ return __float2bfloat16(x); }

__device__ __forceinline__ void gld16(const bf16* g, bf16* l){
  __builtin_amdgcn_global_load_lds(
      (const __attribute__((address_space(1))) void*)g,
      (__attribute__((address_space(3))) void*)l, 16, 0, 0);
}

__device__ __forceinline__ float sigm(float x){ return 1.0f/(1.0f + __expf(-x)); }
__device__ __forceinline__ float tanhfast(float x){
  x = fminf(fmaxf(x, -15.f), 15.f);
  float e = __expf(2.f*x);
  return (e-1.f)/(e+1.f);
}

// ---------------------------------------------------------------------------
// Batched fp32 -> bf16 weight conversion into arena.
// ---------------------------------------------------------------------------
struct CvtPtrs { const float* p[25]; };
__constant__ long CVT_CUM[26] = {0, 98304, 98432, 360576, 360704, 426240,
  426368, 1450368, 1452368, 2476368, 2478368, 3502368, 3504368, 3760368,
  3760496, 4784496, 4786496, 5786496, 5786996, 6042996, 6043124, 7067124,
  7069124, 8069124, 8069624, 8070624};

__global__ __launch_bounds__(256) void cvt_all(CvtPtrs P, bf16* __restrict__ arena)
{
  long g = (long)blockIdx.x * 256 + threadIdx.x;
  if (g >= 8070624l) return;
  int lo = 0, hi = 24;
  while (lo < hi) { int mid = (lo + hi + 1) >> 1; if (g >= CVT_CUM[mid]) lo = mid; else hi = mid - 1; }
  long rel = (g - CVT_CUM[lo]) * 4;
  float4 v = *(const float4*)(P.p[lo] + rel);
  union { bf16 h[4]; uint2 u; } t;
  t.h[0]=f2bf(v.x); t.h[1]=f2bf(v.y); t.h[2]=f2bf(v.z); t.h[3]=f2bf(v.w);
  *(uint2*)(arena + CVT_CUM[lo]*4 + rel) = t.u;
}

// ---------------------------------------------------------------------------
// bt-GEMM, fp32 A / bf16 B: C = A @ Bt^T + bias (bf16 out). 128x128, BK=32.
// K%32==0, M%128==0. All staging addresses hoisted.
// ---------------------------------------------------------------------------
__global__ __launch_bounds__(256) void gemm_linA32(
    const float* __restrict__ A, const bf16* __restrict__ Bt,
    const bf16* __restrict__ bias, bf16* __restrict__ C,
    int M, int N, int K, int lda, int ldb, int ldc)
{
  __shared__ bf16 sm[(128+128)*32];
  bf16* As = sm; bf16* Bs = sm + 128*32;
  const int tid  = threadIdx.x;
  const int wave = tid >> 6, lane = tid & 63;
  const int wr = (wave >> 1) * 64, wc = (wave & 1) * 64;
  const int ln = lane & 15, lq = lane >> 4;
  const long m0 = (long)blockIdx.x * 128;
  const int  n0 = blockIdx.y * 128;

  // hoisted A staging (fp32): thread -> row tid>>1, half (tid&1)*16
  const int arow = tid >> 1, ahalf = (tid & 1) * 16;
  const float* pA = A + (m0 + arow) * (long)lda + ahalf;
  bf16* dA = As + arow * 32 + ahalf;
  // hoisted B staging: slots tid and tid+256
  const int ch = (tid & 3) * 8;
  int colA = n0 + (tid >> 2);       colA = (colA < N) ? colA : (N - 1);
  int colB = n0 + (tid >> 2) + 64;  colB = (colB < N) ? colB : (N - 1);
  const bf16* pB0 = Bt + (long)colA * ldb + ch;
  const bf16* pB1 = Bt + (long)colB * ldb + ch;
  bf16* dB0 = Bs + tid * 8;
  bf16* dB1 = Bs + (tid + 256) * 8;

  f32x4 acc[4][4] = {};
  for (int ks = 0; ks < (K >> 5); ++ks) {
    __syncthreads();
    {  // A: 32 fp32 -> bf16 per thread-half... 16 fp32 per thread
      float4 v0 = *(const float4*)(pA);
      float4 v1 = *(const float4*)(pA + 4);
      float4 v2 = *(const float4*)(pA + 8);
      float4 v3 = *(const float4*)(pA + 12);
      union { bf16 h[16]; short8 q[2]; } u;
      u.h[0]=f2bf(v0.x); u.h[1]=f2bf(v0.y); u.h[2]=f2bf(v0.z); u.h[3]=f2bf(v0.w);
      u.h[4]=f2bf(v1.x); u.h[5]=f2bf(v1.y); u.h[6]=f2bf(v1.z); u.h[7]=f2bf(v1.w);
      u.h[8]=f2bf(v2.x); u.h[9]=f2bf(v2.y); u.h[10]=f2bf(v2.z); u.h[11]=f2bf(v2.w);
      u.h[12]=f2bf(v3.x); u.h[13]=f2bf(v3.y); u.h[14]=f2bf(v3.z); u.h[15]=f2bf(v3.w);
      *(short8*)(dA)     = u.q[0];
      *(short8*)(dA + 8) = u.q[1];
    }
    gld16(pB0, dB0);
    gld16(pB1, dB1);
    __syncthreads();
    short8 af[4], bv[4];
#pragma unroll
    for (int i = 0; i < 4; ++i)
      af[i] = *(const short8*)(As + (wr + i*16 + ln) * 32 + lq * 8);
#pragma unroll
    for (int j = 0; j < 4; ++j)
      bv[j] = *(const short8*)(Bs + (wc + j*16 + ln) * 32 + lq * 8);
#pragma unroll
    for (int i = 0; i < 4; ++i)
#pragma unroll
      for (int j = 0; j < 4; ++j)
        acc[i][j] = __builtin_amdgcn_mfma_f32_16x16x32_bf16(af[i], bv[j], acc[i][j], 0, 0, 0);
    pA += 32; pB0 += 32; pB1 += 32;
  }
#pragma unroll
  for (int j = 0; j < 4; ++j) {
    int n = n0 + wc + j * 16 + ln;
    if (n < N) {
      float bvv = bf2f(bias[n]);
#pragma unroll
      for (int i = 0; i < 4; ++i)
#pragma unroll
        for (int r = 0; r < 4; ++r) {
          long m = m0 + wr + i * 16 + lq * 4 + r;
          C[m * ldc + n] = f2bf(acc[i][j][r] + bvv);
        }
    } else if (n < ldc) {
#pragma unroll
      for (int i = 0; i < 4; ++i)
#pragma unroll
        for (int r = 0; r < 4; ++r) {
          long m = m0 + wr + i * 16 + lq * 4 + r;
          C[m * ldc + n] = f2bf(0.f);
        }
    }
  }
}

// ---------------------------------------------------------------------------
// bt-GEMM, bf16 A / bf16 B. A must be zero-padded over [K, 32*ceil(K/32))
// (ld-2016 buffers guarantee this for K=2000). B overreads past row end by
// <=16 elems are multiplied by A-zeros (and stay inside the weight arena).
// ---------------------------------------------------------------------------
__global__ __launch_bounds__(256) void gemm_lin(
    const bf16* __restrict__ A, const bf16* __restrict__ Bt,
    const bf16* __restrict__ bias, bf16* __restrict__ C,
    int M, int N, int K, int lda, int ldb, int ldc)
{
  __shared__ bf16 sm[(128+128)*32];
  bf16* As = sm; bf16* Bs = sm + 128*32;
  const int tid  = threadIdx.x;
  const int wave = tid >> 6, lane = tid & 63;
  const int wr = (wave >> 1) * 64, wc = (wave & 1) * 64;
  const int ln = lane & 15, lq = lane >> 4;
  const long m0 = (long)blockIdx.x * 128;
  const int  n0 = blockIdx.y * 128;

  const int ch = (tid & 3) * 8;
  const bf16* pA0 = A + (m0 + (tid >> 2)) * (long)lda + ch;
  const bf16* pA1 = A + (m0 + (tid >> 2) + 64) * (long)lda + ch;
  bf16* dA0 = As + tid * 8;
  bf16* dA1 = As + (tid + 256) * 8;
  int colA = n0 + (tid >> 2);       colA = (colA < N) ? colA : (N - 1);
  int colB = n0 + (tid >> 2) + 64;  colB = (colB < N) ? colB : (N - 1);
  const bf16* pB0 = Bt + (long)colA * ldb + ch;
  const bf16* pB1 = Bt + (long)colB * ldb + ch;
  bf16* dB0 = Bs + tid * 8;
  bf16* dB1 = Bs + (tid + 256) * 8;

  f32x4 acc[4][4] = {};
  const int ksteps = (K + 31) >> 5;
  for (int ks = 0; ks < ksteps; ++ks) {
    __syncthreads();
    gld16(pA0, dA0);
    gld16(pA1, dA1);
    gld16(pB0, dB0);
    gld16(pB1, dB1);
    __syncthreads();
    short8 af[4], bv[4];
#pragma unroll
    for (int i = 0; i < 4; ++i)
      af[i] = *(const short8*)(As + (wr + i*16 + ln) * 32 + lq * 8);
#pragma unroll
    for (int j = 0; j < 4; ++j)
      bv[j] = *(const short8*)(Bs + (wc + j*16 + ln) * 32 + lq * 8);
#pragma unroll
    for (int i = 0; i < 4; ++i)
#pragma unroll
      for (int j = 0; j < 4; ++j)
        acc[i][j] = __builtin_amdgcn_mfma_f32_16x16x32_bf16(af[i], bv[j], acc[i][j], 0, 0, 0);
    pA0 += 32; pA1 += 32; pB0 += 32; pB1 += 32;
  }
#pragma unroll
  for (int j = 0; j < 4; ++j) {
    int n = n0 + wc + j * 16 + ln;
    if (n < N) {
      float bvv = bf2f(bias[n]);
#pragma unroll
      for (int i = 0; i < 4; ++i)
#pragma unroll
        for (int r = 0; r < 4; ++r) {
          long m = m0 + wr + i * 16 + lq * 4 + r;
          C[m * ldc + n] = f2bf(acc[i][j][r] + bvv);
        }
    } else if (n < ldc) {
#pragma unroll
      for (int i = 0; i < 4; ++i)
#pragma unroll
        for (int r = 0; r < 4; ++r) {
          long m = m0 + wr + i * 16 + lq * 4 + r;
          C[m * ldc + n] = f2bf(0.f);
        }
    }
  }
}

// ---------------------------------------------------------------------------
// Fused single-step BiLSTM gate GEMM + activation (f-gate dead; h0=c0=0).
// A:[M,512] bf16, W:[8000,512] bf16 arena. Tile 128 rows x 32 h-cols
// (96 gate cols). All staging addresses hoisted out of the 16-step K-loop.
// ---------------------------------------------------------------------------
__global__ __launch_bounds__(256) void gemm_lstm(
    const bf16* __restrict__ A, const bf16* __restrict__ W,
    const bf16* __restrict__ bvec, const bf16* __restrict__ other,
    bf16* __restrict__ Hout, int ldo, int ldc, int combine)
{
  __shared__ bf16 sm[(128+96)*32];
  bf16* As = sm; bf16* Bs = sm + 128*32;
  const int tid  = threadIdx.x;
  const int wave = tid >> 6, lane = tid & 63;
  const int wr = (wave >> 1) * 64, wc = (wave & 1) * 48;
  const int ln = lane & 15, lq = lane >> 4;
  const long m0 = (long)blockIdx.x * 128;
  const int dir = blockIdx.y >> 5, jb = blockIdx.y & 31;

  // hoisted A staging: slots tid, tid+256
  const int ch = (tid & 3) * 8;
  const bf16* pA0 = A + (m0 + (tid >> 2)) * 512 + ch;
  const bf16* pA1 = A + (m0 + (tid >> 2) + 64) * 512 + ch;
  bf16* dA0 = As + tid * 8;
  bf16* dA1 = As + (tid + 256) * 8;
  // hoisted B staging: slot tid (all threads), slot tid+256 (tid<128)
  auto brow = [&](int t) -> long {
    int tc = t >> 2;
    int grp = tc / 48, wi = tc % 48, cf = wi >> 4;
    int jj = jb * 32 + grp * 16 + (wi & 15);
    jj = (jj < 1000) ? jj : 999;
    return (long)(dir * 4000 + cf * 1000 + (cf ? 1000 : 0) + jj);
  };
  const bf16* pB0 = W + brow(tid) * 512 + ch;
  const bf16* pB1 = W + brow(tid + 256) * 512 + ch;   // used only if tid<128
  bf16* dB0 = Bs + tid * 8;
  bf16* dB1 = Bs + (tid + 256) * 8;
  const bool doB1 = (tid < 128);

  f32x4 acc[4][3] = {};
  for (int ks = 0; ks < 16; ++ks) {          // K = 512
    __syncthreads();
    gld16(pA0, dA0);
    gld16(pA1, dA1);
    gld16(pB0, dB0);
    if (doB1) gld16(pB1, dB1);
    __syncthreads();
    short8 af[4], bv[3];
#pragma unroll
    for (int i = 0; i < 4; ++i)
      af[i] = *(const short8*)(As + (wr + i*16 + ln) * 32 + lq * 8);
#pragma unroll
    for (int j = 0; j < 3; ++j)
      bv[j] = *(const short8*)(Bs + (wc + j*16 + ln) * 32 + lq * 8);
#pragma unroll
    for (int i = 0; i < 4; ++i)
#pragma unroll
      for (int j = 0; j < 3; ++j)
        acc[i][j] = __builtin_amdgcn_mfma_f32_16x16x32_bf16(af[i], bv[j], acc[i][j], 0, 0, 0);
    pA0 += 32; pA1 += 32; pB0 += 32; pB1 += 32;
  }
  const int jj  = jb * 32 + (wave & 1) * 16 + ln;
  const int jc  = (jj < 1000) ? jj : 999;
  const float bI = bf2f(bvec[dir * 4000 + jc]);
  const float bG = bf2f(bvec[dir * 4000 + 2000 + jc]);
  const float bO = bf2f(bvec[dir * 4000 + 3000 + jc]);
  const int col = dir * 1000 + jj;
  const bool sv = (jj < 1000);
  const bool sz = (!sv) && (dir == 1) && (col < ldc);
  if (!sv && !sz) return;
#pragma unroll
  for (int i = 0; i < 4; ++i)
#pragma unroll
    for (int r = 0; r < 4; ++r) {
      long m = m0 + wr + i * 16 + lq * 4 + r;
      float h = 0.f;
      if (sv) {
        float gi = acc[i][0][r] + bI;
        float gg = acc[i][1][r] + bG;
        float go = acc[i][2][r] + bO;
        float cc = sigm(gi) * tanhfast(gg);
        h = sigm(go) * tanhfast(cc);
        if (combine) h = 0.5f * (h + bf2f(other[m * ldo + col]));
      }
      Hout[m * ldc + col] = f2bf(h);
    }
}

// mean over 24 neighbors: X [512*24, 2000] bf16 -> Y [512,2000] fp32
__global__ __launch_bounds__(256) void mean24(const bf16* __restrict__ X, float* __restrict__ Y)
{
  long idx = (long)blockIdx.x * 256 + threadIdx.x;
  if (idx >= 512l * 2000) return;
  long b = idx / 2000, e = idx % 2000;
  const bf16* p = X + b * 24 * 2000 + e;
  float s = 0.f;
#pragma unroll
  for (int n = 0; n < 24; ++n) s += bf2f(p[(long)n * 2000]);
  Y[idx] = s * (1.f / 24.f);
}

// attention over {c, u_agg, p_agg} + weighted mix -> out [512,2000] fp32
__global__ __launch_bounds__(256) void attn_mix(
    const bf16* __restrict__ Cm, const float* __restrict__ U,
    const float* __restrict__ P, const float* __restrict__ att,
    float* __restrict__ out)
{
  const int b = blockIdx.x, tid = threadIdx.x;
  __shared__ float red[4][4];
  __shared__ float wsh[3];
  float s0 = 0, s1 = 0, s2 = 0, s3 = 0;
  const long base = (long)b * 2000;
  for (int e = tid; e < 2000; e += 256) {
    float cv = bf2f(Cm[base + e]);
    float al = att[e];
    float ah = att[2000 + e];
    s0 += cv * al; s1 += cv * ah;
    s2 += U[base + e] * ah; s3 += P[base + e] * ah;
  }
#pragma unroll
  for (int o = 32; o; o >>= 1) {
    s0 += __shfl_down(s0, o); s1 += __shfl_down(s1, o);
    s2 += __shfl_down(s2, o); s3 += __shfl_down(s3, o);
  }
  if ((tid & 63) == 0) {
    int w = tid >> 6;
    red[w][0] = s0; red[w][1] = s1; red[w][2] = s2; red[w][3] = s3;
  }
  __syncthreads();
  if (tid == 0) {
    float a0 = 0, a1 = 0, a2 = 0, a3 = 0;
    for (int w = 0; w < 4; ++w) { a0 += red[w][0]; a1 += red[w][1]; a2 += red[w][2]; a3 += red[w][3]; }
    float t0 = a0 + a1, t1 = a0 + a2, t2 = a0 + a3;
    t0 = t0 > 0 ? t0 : 0.01f * t0;
    t1 = t1 > 0 ? t1 : 0.01f * t1;
    t2 = t2 > 0 ? t2 : 0.01f * t2;
    float mx = fmaxf(t0, fmaxf(t1, t2));
    float e0 = __expf(t0 - mx), e1 = __expf(t1 - mx), e2 = __expf(t2 - mx);
    float inv = 1.f / (e0 + e1 + e2);
    wsh[0] = e0 * inv; wsh[1] = e1 * inv; wsh[2] = e2 * inv;
  }
  __syncthreads();
  float w0 = wsh[0], w1 = wsh[1], w2 = wsh[2];
  for (int e = tid; e < 2000; e += 256)
    out[base + e] = w0 * bf2f(Cm[base + e]) + w1 * U[base + e] + w2 * P[base + e];
}

extern "C" void kernel_launch(void* const* d_in, const int* in_sizes, int n_in,
                              void* d_out, int out_size, void* d_ws, size_t ws_size,
                              hipStream_t stream)
{
  const float* c_text  = (const float*)d_in[0];
  const float* c_image = (const float*)d_in[1];
  const float* p_text  = (const float*)d_in[2];
  const float* p_image = (const float*)d_in[3];
  const float* u_text  = (const float*)d_in[4];
  const float* u_other = (const float*)d_in[5];
  const float* p_att   = (const float*)d_in[30];
  float* out = (float*)d_out;

  char* ws = (char*)d_ws;
  size_t off = 0;
  auto alloc = [&](size_t bytes) -> char* {
    char* p = ws + off; off += (bytes + 255) & ~(size_t)255; return p;
  };
  bf16* ARENA = (bf16*)alloc(32282496ull * 2);
  bf16* BIG1  = (bf16*)alloc(12288ull * 2016 * 2);
  bf16* BIG2  = (bf16*)alloc(12288ull * 2016 * 2);
  bf16* X1    = (bf16*)alloc(12288ull * 512 * 2);
  bf16* X2    = (bf16*)alloc(12288ull * 512 * 2);
  bf16* Cc    = (bf16*)alloc(512ull * 2000 * 2);
  float* UA   = (float*)alloc(512ull * 2000 * 4);
  float* PA   = (float*)alloc(512ull * 2000 * 4);
  (void)ws_size; (void)in_sizes; (void)n_in; (void)out_size;

  const bf16* aW_lt = ARENA + 0;        const bf16* ab_lt = ARENA + 393216;
  const bf16* aW_li = ARENA + 393728;   const bf16* ab_li = ARENA + 1442304;
  const bf16* aW_lo = ARENA + 1442816;  const bf16* ab_lo = ARENA + 1704960;
  const bf16* alt_W = ARENA + 1705472;  const bf16* alt_b = ARENA + 5801472;
  const bf16* ali_W = ARENA + 5809472;  const bf16* ali_b = ARENA + 9905472;
  const bf16* alo_W = ARENA + 9913472;  const bf16* alo_b = ARENA + 14009472;
  const bf16* aua_lin_W  = ARENA + 14017472; const bf16* aua_lin_b  = ARENA + 15041472;
  const bf16* aua_lstm_W = ARENA + 15041984; const bf16* aua_lstm_b = ARENA + 19137984;
  const bf16* aua_out_W  = ARENA + 19145984; const bf16* aua_out_b  = ARENA + 23145984;
  const bf16* apa_lin_W  = ARENA + 23147984; const bf16* apa_lin_b  = ARENA + 24171984;
  const bf16* apa_lstm_W = ARENA + 24172496; const bf16* apa_lstm_b = ARENA + 28268496;
  const bf16* apa_out_W  = ARENA + 28276496; const bf16* apa_out_b  = ARENA + 32276496;

  CvtPtrs cp;
  for (int i = 0; i < 25; ++i) cp.p[i] = (const float*)d_in[6 + i];
  cvt_all<<<dim3(31527), dim3(256), 0, stream>>>(cp, ARENA);

  dim3 blk(256);
  // ---- center (post) path, M=512
  gemm_linA32<<<dim3(4,4),  blk, 0, stream>>>(c_text,  aW_lt, ab_lt, X1, 512, 512, 768,  768,  768,  512);
  gemm_linA32<<<dim3(4,4),  blk, 0, stream>>>(c_image, aW_li, ab_li, X2, 512, 512, 2048, 2048, 2048, 512);
  gemm_lstm<<<dim3(4,64), blk, 0, stream>>>(X1, alt_W, alt_b, nullptr, BIG1, 2016, 2016, 0);
  gemm_lstm<<<dim3(4,64), blk, 0, stream>>>(X2, ali_W, ali_b, BIG1,    Cc,   2016, 2000, 1);

  // ---- user path, M=12288
  gemm_linA32<<<dim3(96,4), blk, 0, stream>>>(u_text,  aW_lt, ab_lt, X1, 12288, 512, 768, 768, 768, 512);
  gemm_linA32<<<dim3(96,4), blk, 0, stream>>>(u_other, aW_lo, ab_lo, X2, 12288, 512, 512, 512, 512, 512);
  gemm_lstm<<<dim3(96,64), blk, 0, stream>>>(X1, alt_W, alt_b, nullptr, BIG1, 2016, 2016, 0);
  gemm_lstm<<<dim3(96,64), blk, 0, stream>>>(X2, alo_W, alo_b, BIG1,    BIG2, 2016, 2016, 1);
  gemm_lin<<<dim3(96,4), blk, 0, stream>>>(BIG2, aua_lin_W, aua_lin_b, X1, 12288, 512, 2000, 2016, 2000, 512);
  gemm_lstm<<<dim3(96,64), blk, 0, stream>>>(X1, aua_lstm_W, aua_lstm_b, nullptr, BIG1, 2016, 2016, 0);
  gemm_lin<<<dim3(96,16), blk, 0, stream>>>(BIG1, aua_out_W, aua_out_b, BIG2, 12288, 2000, 2000, 2016, 2000, 2000);
  mean24<<<dim3(4000), blk, 0, stream>>>(BIG2, UA);

  // ---- post-neighbor path, M=12288
  gemm_linA32<<<dim3(96,4), blk, 0, stream>>>(p_text,  aW_lt, ab_lt, X1, 12288, 512, 768,  768,  768,  512);
  gemm_linA32<<<dim3(96,4), blk, 0, stream>>>(p_image, aW_li, ab_li, X2, 12288, 512, 2048, 2048, 2048, 512);
  gemm_lstm<<<dim3(96,64), blk, 0, stream>>>(X1, alt_W, alt_b, nullptr, BIG1, 2016, 2016, 0);
  gemm_lstm<<<dim3(96,64), blk, 0, stream>>>(X2, ali_W, ali_b, BIG1,    BIG2, 2016, 2016, 1);
  gemm_lin<<<dim3(96,4), blk, 0, stream>>>(BIG2, apa_lin_W, apa_lin_b, X1, 12288, 512, 2000, 2016, 2000, 512);
  gemm_lstm<<<dim3(96,64), blk, 0, stream>>>(X1, apa_lstm_W, apa_lstm_b, nullptr, BIG1, 2016, 2016, 0);
  gemm_lin<<<dim3(96,16), blk, 0, stream>>>(BIG1, apa_out_W, apa_out_b, BIG2, 12288, 2000, 2000, 2016, 2000, 2000);
  mean24<<<dim3(4000), blk, 0, stream>>>(BIG2, PA);

  // ---- attention + mix (fp32 out)
  attn_mix<<<dim3(512), blk, 0, stream>>>(Cc, UA, PA, p_att, out);
}